// Round 5
// baseline (93.647 us; speedup 1.0000x reference)
//
#include <hip/hip_runtime.h>

typedef float f4 __attribute__((ext_vector_type(4)));   // native vector, OK for nontemporal builtins

static constexpr int DIM     = 192;
static constexpr int NVOX    = 2 * DIM * DIM * DIM;   // 14,155,776
static constexpr int N8      = NVOX / 8;              // 1,769,472
static constexpr int TSIZE   = NVOX;
static constexpr int RBLOCKS = 256;
static constexpr int RTHREADS = 1024;
// ws layout (floats): [0 .. RBLOCKS*8) per-block partials

// ---------------- Kernel 1: per-block partial reductions ----------------
__global__ __launch_bounds__(1024) void com_reduce(const float* __restrict__ x,
                                                   const float* __restrict__ y,
                                                   float* __restrict__ ws) {
    const float step = 2.0f / 191.0f;
    float a0 = 0, a1 = 0, a2 = 0, a3 = 0;
    float b0 = 0, b1 = 0, b2 = 0, b3 = 0;

    for (int t8 = blockIdx.x * RTHREADS + threadIdx.x; t8 < N8;
         t8 += RBLOCKS * RTHREADS) {
        int idx = t8 * 8;
        int k = idx % DIM;               // multiple of 8
        int r = idx / DIM;
        int j = r % DIM;
        int i = (r / DIM) % DIM;

        const f4* xp = reinterpret_cast<const f4*>(x) + t8 * 2;
        const f4* yp = reinterpret_cast<const f4*>(y) + t8 * 2;
        f4 x0 = __builtin_nontemporal_load(xp);
        f4 x1 = __builtin_nontemporal_load(xp + 1);
        f4 y0 = __builtin_nontemporal_load(yp);
        f4 y1 = __builtin_nontemporal_load(yp + 1);

        float g[8];
#pragma unroll
        for (int u = 0; u < 8; ++u) g[u] = fmaf((float)(k + u), step, -1.0f);
        float gj = fmaf((float)j, step, -1.0f);
        float gi = fmaf((float)i, step, -1.0f);

        float xs = ((x0.x + x0.y) + (x0.z + x0.w)) + ((x1.x + x1.y) + (x1.z + x1.w));
        float ys = ((y0.x + y0.y) + (y0.z + y0.w)) + ((y1.x + y1.y) + (y1.z + y1.w));
        float xg = ((x0.x * g[0] + x0.y * g[1]) + (x0.z * g[2] + x0.w * g[3]))
                 + ((x1.x * g[4] + x1.y * g[5]) + (x1.z * g[6] + x1.w * g[7]));
        float yg = ((y0.x * g[0] + y0.y * g[1]) + (y0.z * g[2] + y0.w * g[3]))
                 + ((y1.x * g[4] + y1.y * g[5]) + (y1.z * g[6] + y1.w * g[7]));

        a0 += xs;  a1 += xg;  a2 += xs * gj;  a3 += xs * gi;
        b0 += ys;  b1 += yg;  b2 += ys * gj;  b3 += ys * gi;
    }

    float v[8] = {a0, a1, a2, a3, b0, b1, b2, b3};
#pragma unroll
    for (int q = 0; q < 8; ++q) {
#pragma unroll
        for (int off = 32; off > 0; off >>= 1)
            v[q] += __shfl_down(v[q], off, 64);
    }

    __shared__ float sm[16][8];
    int lane = threadIdx.x & 63;
    int wave = threadIdx.x >> 6;
    if (lane == 0) {
#pragma unroll
        for (int q = 0; q < 8; ++q) sm[wave][q] = v[q];
    }
    __syncthreads();
    if (threadIdx.x < 8) {
        float s = 0;
#pragma unroll
        for (int w = 0; w < 16; ++w) s += sm[w][threadIdx.x];
        ws[blockIdx.x * 8 + threadIdx.x] = s;
    }
}

// ---------------- Kernel 2: prologue-finalize + LDS-staged trilinear + grid ----------------
// block = (b, i, 8 consecutive j). 384 threads, tile = 1536 voxels.
__global__ __launch_bounds__(384) void com_apply(const float* __restrict__ x,
                                                 float* __restrict__ out,
                                                 const float* __restrict__ wsp) {
    __shared__ double sd[6][8];
    __shared__ float  sp[16];
    __shared__ float  srow[9][240];    // data at cols [16,208); pads zeroed

    int tid = threadIdx.x;

    // zero LDS pads (independent of params)
    for (int p = tid; p < 432; p += 384) {
        int m = p / 48, cc = p % 48;
        int col = (cc < 16) ? cc : (cc - 16 + 208);
        srow[m][col] = 0.0f;
    }

    // distributed finalize: sum 2048 partials (q = tid&7 is invariant: 384%8==0)
    {
        double s = 0;
        for (int idx = tid; idx < RBLOCKS * 8; idx += 384)
            s += (double)wsp[idx];
        s += __shfl_xor(s, 8, 64);
        s += __shfl_xor(s, 16, 64);
        s += __shfl_xor(s, 32, 64);
        int lane = tid & 63, wave = tid >> 6;
        if (lane < 8) sd[wave][lane] = s;
    }
    __syncthreads();
    if (tid == 0) {
        double t[8];
#pragma unroll
        for (int q = 0; q < 8; ++q) {
            double s = 0;
#pragma unroll
            for (int w = 0; w < 6; ++w) s += sd[w][q];
            t[q] = s;
        }
        double tx = t[1] / t[0] - t[5] / t[4];
        double ty = t[2] / t[0] - t[6] / t[4];
        double tz = t[3] / t[0] - t[7] / t[4];
        double sx = tx * 95.5, sy = ty * 95.5, sz = tz * 95.5;
        double fsx = floor(sx), fsy = floor(sy), fsz = floor(sz);
        sp[0] = (float)(sx - fsx);
        sp[1] = (float)(sy - fsy);
        sp[2] = (float)(sz - fsz);
        sp[3] = (float)tx;
        sp[4] = (float)ty;
        sp[5] = (float)tz;
        int* ip = reinterpret_cast<int*>(sp + 6);
        ip[0] = (int)fsx; ip[1] = (int)fsy; ip[2] = (int)fsz;
    }
    __syncthreads();

    float fx = sp[0], fy = sp[1], fz = sp[2];
    float txf = sp[3], tyf = sp[4], tzf = sp[5];
    const int* ip = reinterpret_cast<const int*>(sp + 6);
    int iox = ip[0], ioy = ip[1], ioz = ip[2];

    int bid = blockIdx.x;
    int jg = bid % 24;
    int i  = (bid / 24) % DIM;
    int b  = bid / (24 * DIM);
    int j0 = jg * 8;

    int z0 = i + ioz, z1 = z0 + 1;
    float wz0 = (z0 >= 0 && z0 < DIM) ? 1.0f - fz : 0.0f;
    float wz1 = (z1 >= 0 && z1 < DIM) ? fz : 0.0f;
    int zc0 = min(max(z0, 0), DIM - 1), zc1 = min(max(z1, 0), DIM - 1);

    const float* xb = x + (size_t)b * (DIM * DIM * DIM);
    for (int task = tid; task < 432; task += 384) {
        int m = task / 48;
        int c = (task % 48) * 4;
        int yv = j0 + ioy + m;
        int yc = min(max(yv, 0), DIM - 1);
        const f4* p0 = reinterpret_cast<const f4*>(xb + (zc0 * DIM + yc) * DIM + c);
        const f4* p1 = reinterpret_cast<const f4*>(xb + (zc1 * DIM + yc) * DIM + c);
        f4 va = *p0;
        f4 vb = *p1;
        f4 s = wz0 * va + wz1 * vb;
        *reinterpret_cast<f4*>(&srow[m][16 + c]) = s;
    }
    __syncthreads();

    int rr = tid / 48;
    int k4 = tid % 48;
    int k  = k4 * 4;
    int j  = j0 + rr;
    int yv0 = j + ioy, yv1 = yv0 + 1;
    float wy0 = (yv0 >= 0 && yv0 < DIM) ? 1.0f - fy : 0.0f;
    float wy1 = (yv1 >= 0 && yv1 < DIM) ? fy : 0.0f;

    float wx0[4], wx1[4];
#pragma unroll
    for (int m = 0; m < 4; ++m) {
        int c0 = k + m + iox, c1 = c0 + 1;
        wx0[m] = (c0 >= 0 && c0 < DIM) ? 1.0f - fx : 0.0f;
        wx1[m] = (c1 >= 0 && c1 < DIM) ? fx : 0.0f;
    }

    int a  = iox & 3;                 // wave-uniform
    int cb = 16 + k + (iox - a);      // 16B-aligned LDS float index
    float f0[8], f1[8];
    *reinterpret_cast<f4*>(&f0[0]) = *reinterpret_cast<const f4*>(&srow[rr][cb]);
    *reinterpret_cast<f4*>(&f0[4]) = *reinterpret_cast<const f4*>(&srow[rr][cb + 4]);
    *reinterpret_cast<f4*>(&f1[0]) = *reinterpret_cast<const f4*>(&srow[rr + 1][cb]);
    *reinterpret_cast<f4*>(&f1[4]) = *reinterpret_cast<const f4*>(&srow[rr + 1][cb + 4]);

    float res[4];
#define DOCASE(A)                                                           \
    _Pragma("unroll")                                                       \
    for (int m = 0; m < 4; ++m) {                                           \
        float u0 = wy0 * f0[A + m]     + wy1 * f1[A + m];                   \
        float u1 = wy0 * f0[A + m + 1] + wy1 * f1[A + m + 1];               \
        res[m] = wx0[m] * u0 + wx1[m] * u1;                                 \
    }
    switch (a) {
        case 0: DOCASE(0); break;
        case 1: DOCASE(1); break;
        case 2: DOCASE(2); break;
        default: DOCASE(3); break;
    }
#undef DOCASE

    f4 tr = {res[0], res[1], res[2], res[3]};
    __builtin_nontemporal_store(tr, reinterpret_cast<f4*>(out) + bid * 384 + tid);

    // grid output: region floats [TSIZE + bid*4608, +4608) = 1152 float4
    const float step = 2.0f / 191.0f;
    float gzv = fmaf((float)i, step, -1.0f) + tzf;   // comp 2, block-constant
    int g4base = TSIZE / 4 + bid * 1152;
#pragma unroll
    for (int s = 0; s < 3; ++s) {
        f4 gv;
#pragma unroll
        for (int u = 0; u < 4; ++u) {
            int L = (tid + s * 384) * 4 + u;   // local float index
            int lv = L / 3;                    // local voxel 0..1535
            int comp = L - lv * 3;
            int kk = lv % DIM;
            int rj = lv / DIM;                 // 0..7
            float val;
            if (comp == 0)      val = fmaf((float)kk, step, -1.0f) + txf;
            else if (comp == 1) val = fmaf((float)(j0 + rj), step, -1.0f) + tyf;
            else                val = gzv;
            gv[u] = val;
        }
        __builtin_nontemporal_store(gv, reinterpret_cast<f4*>(out) + g4base + tid + s * 384);
    }
}

extern "C" void kernel_launch(void* const* d_in, const int* in_sizes, int n_in,
                              void* d_out, int out_size, void* d_ws, size_t ws_size,
                              hipStream_t stream) {
    const float* x = (const float*)d_in[0];
    const float* y = (const float*)d_in[1];
    float* out = (float*)d_out;
    float* ws = (float*)d_ws;

    com_reduce<<<RBLOCKS, RTHREADS, 0, stream>>>(x, y, ws);
    com_apply<<<NVOX / 1536, 384, 0, stream>>>(x, out, ws);
}

// Round 6
// 89.744 us; speedup vs baseline: 1.0435x; 1.0435x over previous
//
#include <hip/hip_runtime.h>

typedef float f4 __attribute__((ext_vector_type(4)));

static constexpr int DIM      = 192;
static constexpr int NVOX     = 2 * DIM * DIM * DIM;   // 14,155,776
static constexpr int N8       = NVOX / 8;              // 1,769,472
static constexpr int TSIZE    = NVOX;
static constexpr int RBLOCKS  = 256;
static constexpr int RTHREADS = 1024;
// ws layout (floats): [0..5] fx,fy,fz,tx,ty,tz ; [6..8] iox,ioy,ioz (int bits)
//                     [16 .. 16+RBLOCKS*8) per-block partials

// ---------------- Kernel 1: per-block partial reductions ----------------
__global__ __launch_bounds__(1024) void com_reduce(const float* __restrict__ x,
                                                   const float* __restrict__ y,
                                                   float* __restrict__ ws) {
    const float step = 2.0f / 191.0f;
    float a0 = 0, a1 = 0, a2 = 0, a3 = 0;
    float b0 = 0, b1 = 0, b2 = 0, b3 = 0;

    for (int t8 = blockIdx.x * RTHREADS + threadIdx.x; t8 < N8;
         t8 += RBLOCKS * RTHREADS) {
        int idx = t8 * 8;
        int k = idx % DIM;               // multiple of 8
        int r = idx / DIM;
        int j = r % DIM;
        int i = (r / DIM) % DIM;

        const f4* xp = reinterpret_cast<const f4*>(x) + t8 * 2;
        const f4* yp = reinterpret_cast<const f4*>(y) + t8 * 2;
        f4 x0 = xp[0];                               // plain: keep x L3-resident
        f4 x1 = xp[1];
        f4 y0 = __builtin_nontemporal_load(yp);      // y never re-read
        f4 y1 = __builtin_nontemporal_load(yp + 1);

        float g[8];
#pragma unroll
        for (int u = 0; u < 8; ++u) g[u] = fmaf((float)(k + u), step, -1.0f);
        float gj = fmaf((float)j, step, -1.0f);
        float gi = fmaf((float)i, step, -1.0f);

        float xs = ((x0.x + x0.y) + (x0.z + x0.w)) + ((x1.x + x1.y) + (x1.z + x1.w));
        float ys = ((y0.x + y0.y) + (y0.z + y0.w)) + ((y1.x + y1.y) + (y1.z + y1.w));
        float xg = ((x0.x * g[0] + x0.y * g[1]) + (x0.z * g[2] + x0.w * g[3]))
                 + ((x1.x * g[4] + x1.y * g[5]) + (x1.z * g[6] + x1.w * g[7]));
        float yg = ((y0.x * g[0] + y0.y * g[1]) + (y0.z * g[2] + y0.w * g[3]))
                 + ((y1.x * g[4] + y1.y * g[5]) + (y1.z * g[6] + y1.w * g[7]));

        a0 += xs;  a1 += xg;  a2 += xs * gj;  a3 += xs * gi;
        b0 += ys;  b1 += yg;  b2 += ys * gj;  b3 += ys * gi;
    }

    float v[8] = {a0, a1, a2, a3, b0, b1, b2, b3};
#pragma unroll
    for (int q = 0; q < 8; ++q) {
#pragma unroll
        for (int off = 32; off > 0; off >>= 1)
            v[q] += __shfl_down(v[q], off, 64);
    }

    __shared__ float sm[16][8];
    int lane = threadIdx.x & 63;
    int wave = threadIdx.x >> 6;
    if (lane == 0) {
#pragma unroll
        for (int q = 0; q < 8; ++q) sm[wave][q] = v[q];
    }
    __syncthreads();
    if (threadIdx.x < 8) {
        float s = 0;
#pragma unroll
        for (int w = 0; w < 16; ++w) s += sm[w][threadIdx.x];
        ws[16 + blockIdx.x * 8 + threadIdx.x] = s;
    }
}

// ---------------- Kernel 1.5: fold partials into sampling params ----------------
__global__ __launch_bounds__(256) void com_finalize(float* __restrict__ ws) {
    __shared__ double sd[256];
    int t = threadIdx.x;
    int q = t & 7;
    double s = 0;
    for (int p = t >> 3; p < RBLOCKS; p += 32)
        s += (double)ws[16 + p * 8 + q];
    sd[t] = s;
    __syncthreads();
    for (int off = 128; off >= 8; off >>= 1) {
        if (t < off) sd[t] += sd[t + off];
        __syncthreads();
    }
    if (t == 0) {
        double xs = sd[0], xgx = sd[1], xgy = sd[2], xgz = sd[3];
        double ys = sd[4], ygx = sd[5], ygy = sd[6], ygz = sd[7];
        double tx = xgx / xs - ygx / ys;
        double ty = xgy / xs - ygy / ys;
        double tz = xgz / xs - ygz / ys;
        double sx = tx * 95.5, sy = ty * 95.5, sz = tz * 95.5;
        double fsx = floor(sx), fsy = floor(sy), fsz = floor(sz);
        ws[0] = (float)(sx - fsx);
        ws[1] = (float)(sy - fsy);
        ws[2] = (float)(sz - fsz);
        ws[3] = (float)tx;
        ws[4] = (float)ty;
        ws[5] = (float)tz;
        int* ip = reinterpret_cast<int*>(ws + 6);
        ip[0] = (int)fsx; ip[1] = (int)fsy; ip[2] = (int)fsz;
    }
}

// ---------------- Kernel A: LDS-staged trilinear sample only ----------------
// block = (b, i, 8 consecutive j). 384 threads, tile = 1536 voxels.
__global__ __launch_bounds__(384) void com_sample(const float* __restrict__ x,
                                                  float* __restrict__ out,
                                                  const float* __restrict__ ws) {
    float fx = ws[0], fy = ws[1], fz = ws[2];
    const int* ip = reinterpret_cast<const int*>(ws + 6);
    int iox = ip[0], ioy = ip[1], ioz = ip[2];

    __shared__ float srow[9][240];   // data at cols [16,208); pads zeroed
    int tid = threadIdx.x;

    for (int p = tid; p < 432; p += 384) {
        int m = p / 48, cc = p % 48;
        int col = (cc < 16) ? cc : (cc - 16 + 208);
        srow[m][col] = 0.0f;
    }

    int bid = blockIdx.x;
    int jg = bid % 24;
    int i  = (bid / 24) % DIM;
    int b  = bid / (24 * DIM);
    int j0 = jg * 8;

    int z0 = i + ioz, z1 = z0 + 1;
    float wz0 = (z0 >= 0 && z0 < DIM) ? 1.0f - fz : 0.0f;
    float wz1 = (z1 >= 0 && z1 < DIM) ? fz : 0.0f;
    int zc0 = min(max(z0, 0), DIM - 1), zc1 = min(max(z1, 0), DIM - 1);

    const float* xb = x + (size_t)b * (DIM * DIM * DIM);
    for (int task = tid; task < 432; task += 384) {
        int m = task / 48;
        int c = (task % 48) * 4;
        int yv = j0 + ioy + m;
        int yc = min(max(yv, 0), DIM - 1);
        f4 va = *reinterpret_cast<const f4*>(xb + (zc0 * DIM + yc) * DIM + c);
        f4 vb = *reinterpret_cast<const f4*>(xb + (zc1 * DIM + yc) * DIM + c);
        *reinterpret_cast<f4*>(&srow[m][16 + c]) = wz0 * va + wz1 * vb;
    }
    __syncthreads();

    int rr = tid / 48;
    int k4 = tid % 48;
    int k  = k4 * 4;
    int j  = j0 + rr;
    int yv0 = j + ioy, yv1 = yv0 + 1;
    float wy0 = (yv0 >= 0 && yv0 < DIM) ? 1.0f - fy : 0.0f;
    float wy1 = (yv1 >= 0 && yv1 < DIM) ? fy : 0.0f;

    float wx0[4], wx1[4];
#pragma unroll
    for (int m = 0; m < 4; ++m) {
        int c0 = k + m + iox, c1 = c0 + 1;
        wx0[m] = (c0 >= 0 && c0 < DIM) ? 1.0f - fx : 0.0f;
        wx1[m] = (c1 >= 0 && c1 < DIM) ? fx : 0.0f;
    }

    int a  = iox & 3;                 // wave-uniform
    int cb = 16 + k + (iox - a);      // 16B-aligned LDS float index
    float f0[8], f1[8];
    *reinterpret_cast<f4*>(&f0[0]) = *reinterpret_cast<const f4*>(&srow[rr][cb]);
    *reinterpret_cast<f4*>(&f0[4]) = *reinterpret_cast<const f4*>(&srow[rr][cb + 4]);
    *reinterpret_cast<f4*>(&f1[0]) = *reinterpret_cast<const f4*>(&srow[rr + 1][cb]);
    *reinterpret_cast<f4*>(&f1[4]) = *reinterpret_cast<const f4*>(&srow[rr + 1][cb + 4]);

    float res[4];
#define DOCASE(A)                                                           \
    _Pragma("unroll")                                                       \
    for (int m = 0; m < 4; ++m) {                                           \
        float u0 = wy0 * f0[A + m]     + wy1 * f1[A + m];                   \
        float u1 = wy0 * f0[A + m + 1] + wy1 * f1[A + m + 1];               \
        res[m] = wx0[m] * u0 + wx1[m] * u1;                                 \
    }
    switch (a) {
        case 0: DOCASE(0); break;
        case 1: DOCASE(1); break;
        case 2: DOCASE(2); break;
        default: DOCASE(3); break;
    }
#undef DOCASE

    f4 tr = {res[0], res[1], res[2], res[3]};
    __builtin_nontemporal_store(tr, reinterpret_cast<f4*>(out) + bid * 384 + tid);
}

// ---------------- Kernel B: grid fill (pure write stream) ----------------
// thread handles 3 float4 at stride 256 within its block's 768-float4 region.
__global__ __launch_bounds__(256) void com_grid(float* __restrict__ out,
                                                const float* __restrict__ ws) {
    float txf = ws[3], tyf = ws[4], tzf = ws[5];
    const float step = 2.0f / 191.0f;
    int tid = threadIdx.x;
    int bid = blockIdx.x;
    int g4base = TSIZE / 4 + bid * 768;

#pragma unroll
    for (int s = 0; s < 3; ++s) {
        int f4idx = bid * 768 + s * 256 + tid;   // f4 index within grid region
        f4 gv;
#pragma unroll
        for (int u = 0; u < 4; ++u) {
            int L = f4idx * 4 + u;               // float index in grid region
            int lv = L / 3;                      // voxel index (0..NVOX-1)
            int comp = L - lv * 3;
            int kk = lv % DIM;
            int r  = lv / DIM;
            int jj = r % DIM;
            int ii = (r / DIM) % DIM;            // same for both batches
            float val;
            if (comp == 0)      val = fmaf((float)kk, step, -1.0f) + txf;
            else if (comp == 1) val = fmaf((float)jj, step, -1.0f) + tyf;
            else                val = fmaf((float)ii, step, -1.0f) + tzf;
            gv[u] = val;
        }
        __builtin_nontemporal_store(gv, reinterpret_cast<f4*>(out) + g4base + s * 256 + tid);
    }
}

extern "C" void kernel_launch(void* const* d_in, const int* in_sizes, int n_in,
                              void* d_out, int out_size, void* d_ws, size_t ws_size,
                              hipStream_t stream) {
    const float* x = (const float*)d_in[0];
    const float* y = (const float*)d_in[1];
    float* out = (float*)d_out;
    float* ws = (float*)d_ws;

    com_reduce<<<RBLOCKS, RTHREADS, 0, stream>>>(x, y, ws);
    com_finalize<<<1, 256, 0, stream>>>(ws);
    com_sample<<<NVOX / 1536, 384, 0, stream>>>(x, out, ws);
    // grid region = 3*NVOX floats = 10,616,832 float4; 768 f4/block -> 13,824 blocks
    com_grid<<<(3 * NVOX / 4) / 768, 256, 0, stream>>>(out, ws);
}